// Round 1
// baseline (6387.705 us; speedup 1.0000x reference)
//
#include <hip/hip_runtime.h>
#include <hip/hip_bf16.h>

#define SEQ 2048
#define EMB 1024
#define HID 1024
#define G4  4096
#define VOC 50257
#define VPAD 50304   // 393 * 128
#define KDIM 1024

typedef short bhalf8 __attribute__((ext_vector_type(8)));
typedef float f32x4  __attribute__((ext_vector_type(4)));

typedef __attribute__((address_space(3))) void lds_void;
typedef __attribute__((address_space(1))) const void gbl_cvoid;

__device__ __forceinline__ void direct_lds16(void* lds, const void* g) {
    __builtin_amdgcn_global_load_lds((gbl_cvoid*)g, (lds_void*)lds, 16, 0, 0);
}

__device__ __forceinline__ unsigned short f2b(float f) {
    unsigned u = __float_as_uint(f);
    unsigned r = u + 0x7fffu + ((u >> 16) & 1u);
    return (unsigned short)(r >> 16);
}

// ---------------- f32 -> bf16 convert (with zero padding past n_src) ----------------
__global__ void f32_to_bf16_k(const float* __restrict__ src, unsigned short* __restrict__ dst,
                              long n_src, long n_dst) {
    long i = ((long)blockIdx.x * 256 + threadIdx.x) * 4;
    if (i >= n_dst) return;
    unsigned short o0 = 0, o1 = 0, o2 = 0, o3 = 0;
    if (i < n_src) {
        f32x4 v = *(const f32x4*)&src[i];
        o0 = f2b(v[0]); o1 = f2b(v[1]); o2 = f2b(v[2]); o3 = f2b(v[3]);
    }
    ushort4 o; o.x = o0; o.y = o1; o.z = o2; o.w = o3;
    *(ushort4*)&dst[i] = o;
}

// ---------------- embedding gather + bf16 ----------------
__global__ void embed_cvt_k(const int* __restrict__ seq, const float* __restrict__ emb,
                            unsigned short* __restrict__ xb) {
    int s = blockIdx.x;
    int k = threadIdx.x * 4;
    long row = (long)seq[s] * EMB;
    f32x4 v = *(const f32x4*)&emb[row + k];
    ushort4 o; o.x = f2b(v[0]); o.y = f2b(v[1]); o.z = f2b(v[2]); o.w = f2b(v[3]);
    *(ushort4*)&xb[(long)s * EMB + k] = o;
}

__global__ void bias_sum_k(const float* __restrict__ a, const float* __restrict__ b,
                           float* __restrict__ o) {
    int i = blockIdx.x * 256 + threadIdx.x;
    if (i < G4) o[i] = a[i] + b[i];
}

// ---------------- bf16 BT-GEMM: C[M,N] = A[M,K] @ Bt[N,K]^T + bias ----------------
// A, Bt row-major bf16 (K contiguous). 128x128 tile, BK=64, 256 threads (4 waves, 2x2 of 64x64).
// Staging via global_load_lds width=16 (wave-uniform LDS base + lane*16).
__global__ __launch_bounds__(256)
void gemm_bt_k(const unsigned short* __restrict__ A, const unsigned short* __restrict__ Bt,
               const float* __restrict__ bias, float* __restrict__ C,
               int M, int Nreal, int K, int ldc) {
    __shared__ unsigned short lA[128 * 64];
    __shared__ unsigned short lB[128 * 64];
    const int tid  = threadIdx.x;
    const int wave = tid >> 6;
    const int lane = tid & 63;
    const int m0 = blockIdx.x * 128;   // x = M tile (16 of them) -> B tile reused by consecutive blocks
    const int n0 = blockIdx.y * 128;
    const int wm = (wave >> 1) * 64;
    const int wn = (wave & 1) * 64;
    const int quad = lane >> 4, l16 = lane & 15;
    const int srow = lane >> 3;          // 0..7 row within 8-row staging slab
    const int scol = (lane & 7) * 8;     // ushort col within 64-wide row

    f32x4 acc[4][4] = {};

    for (int k0 = 0; k0 < K; k0 += 64) {
#pragma unroll
        for (int c = 0; c < 4; ++c) {
            int r0 = wave * 32 + c * 8;  // wave-uniform
            const unsigned short* ga = A  + (long)(m0 + r0 + srow) * K + k0 + scol;
            direct_lds16(&lA[r0 * 64], ga);
            const unsigned short* gb = Bt + (long)(n0 + r0 + srow) * K + k0 + scol;
            direct_lds16(&lB[r0 * 64], gb);
        }
        __syncthreads();
#pragma unroll
        for (int kk = 0; kk < 2; ++kk) {
            bhalf8 af[4], bf[4];
#pragma unroll
            for (int i = 0; i < 4; ++i) {
                af[i] = *(const bhalf8*)&lA[(wm + i * 16 + l16) * 64 + kk * 32 + quad * 8];
                bf[i] = *(const bhalf8*)&lB[(wn + i * 16 + l16) * 64 + kk * 32 + quad * 8];
            }
#pragma unroll
            for (int i = 0; i < 4; ++i)
#pragma unroll
                for (int j = 0; j < 4; ++j)
                    acc[i][j] = __builtin_amdgcn_mfma_f32_16x16x32_bf16(af[i], bf[j], acc[i][j], 0, 0, 0);
        }
        __syncthreads();
    }
    // epilogue: C/D layout col=lane&15, row=quad*4+reg (m89/m91-verified)
#pragma unroll
    for (int i = 0; i < 4; ++i) {
        int gm = m0 + wm + i * 16 + quad * 4;
#pragma unroll
        for (int j = 0; j < 4; ++j) {
            int gn = n0 + wn + j * 16 + l16;
            if (gn < Nreal) {
                float bv = bias[gn];
#pragma unroll
                for (int r = 0; r < 4; ++r)
                    C[(long)(gm + r) * ldc + gn] = acc[i][j][r] + bv;
            }
        }
    }
}

// ---------------- persistent LSTM recurrence ----------------
// 256 WGs x 256 threads. WG owns 4 hidden units (16 gate rows). W_hh rows in VGPRs
// (16 x f32x4 per thread). h broadcast via tag-packed uint64 agent-scope atomics.
__global__ __launch_bounds__(256, 1)
void lstm_seq_k(const float* __restrict__ W_hh, const float* __restrict__ xg,
                unsigned short* __restrict__ hs_b, unsigned long long* __restrict__ hbuf) {
    const int tid = threadIdx.x;
    const int wg  = blockIdx.x;          // 0..255
    const int lr  = tid >> 4;            // 0..15 local gate-row
    const int seg = tid & 15;            // col segment
    const int gate = lr >> 2;            // == wave id
    const int ul   = lr & 3;             // local unit
    const int u    = wg * 4 + ul;
    const int grow = gate * HID + u;     // W_hh row

    __shared__ float h_lds[HID];
    __shared__ float g_lds[4][4];

    f32x4 w[16];
#pragma unroll
    for (int m = 0; m < 16; ++m)
        w[m] = *(const f32x4*)&W_hh[(long)grow * HID + (m * 16 + seg) * 4];

#pragma unroll
    for (int q = 0; q < 4; ++q) h_lds[tid + q * 256] = 0.f;
    float c = 0.f;   // persistent cell state, valid for tid<4
    __syncthreads();

    for (int t = 0; t < SEQ; ++t) {
        float xgv = (seg == 0) ? xg[(long)t * G4 + grow] : 0.f;
        if (t > 0) {
            const unsigned long long want = (unsigned long long)t;
            unsigned long long* src = &hbuf[((t - 1) & 1) * HID];
#pragma unroll
            for (int q = 0; q < 4; ++q) {
                int e = tid + q * 256;
                unsigned long long v;
                do {
                    v = __hip_atomic_load(&src[e], __ATOMIC_RELAXED, __HIP_MEMORY_SCOPE_AGENT);
                } while ((v >> 32) != want);
                h_lds[e] = __uint_as_float((unsigned)v);
            }
        }
        __syncthreads();

        float acc = 0.f;
        const f32x4* h4 = (const f32x4*)h_lds;
#pragma unroll
        for (int m = 0; m < 16; ++m) {
            f32x4 hv = h4[m * 16 + seg];   // conflict-light strided layout
            acc += w[m][0] * hv[0] + w[m][1] * hv[1] + w[m][2] * hv[2] + w[m][3] * hv[3];
        }
        acc += __shfl_xor(acc, 8);
        acc += __shfl_xor(acc, 4);
        acc += __shfl_xor(acc, 2);
        acc += __shfl_xor(acc, 1);

        if (seg == 0) {
            float g = acc + xgv;
            float a = (gate == 2) ? tanhf(g) : 1.f / (1.f + __expf(-g));  // wave-uniform branch
            g_lds[gate][ul] = a;
        }
        __syncthreads();
        if (tid < 4) {
            float iv = g_lds[0][tid], fv = g_lds[1][tid], gv = g_lds[2][tid], ov = g_lds[3][tid];
            c = fv * c + iv * gv;
            float h = ov * tanhf(c);
            int ug = wg * 4 + tid;
            hs_b[(long)t * HID + ug] = f2b(h);
            unsigned long long pk = ((unsigned long long)(t + 1) << 32) | (unsigned long long)__float_as_uint(h);
            __hip_atomic_store(&hbuf[(t & 1) * HID + ug], pk, __ATOMIC_RELAXED, __HIP_MEMORY_SCOPE_AGENT);
        }
        __syncthreads();
    }
}

// ---------------- in-place log_softmax over rows of [SEQ][VOC] ----------------
__global__ __launch_bounds__(256)
void log_softmax_k(float* __restrict__ X) {
    const int tid = threadIdx.x;
    const long base = (long)blockIdx.x * VOC;
    float* p = X + base;
    const int head = (4 - (int)(base & 3)) & 3;
    const int n4 = (VOC - head) >> 2;
    const int tail_start = head + n4 * 4;
    f32x4* p4 = (f32x4*)(p + head);

    float m = -INFINITY, s = 0.f;
    auto upd = [&](float x) {
        float nm = fmaxf(m, x);
        s = s * __expf(m - nm) + __expf(x - nm);
        m = nm;
    };
    for (int i = tid; i < n4; i += 256) {
        f32x4 v = p4[i];
        upd(v[0]); upd(v[1]); upd(v[2]); upd(v[3]);
    }
    if (tid == 0) {
        for (int i = 0; i < head; ++i) upd(p[i]);
        for (int i = tail_start; i < VOC; ++i) upd(p[i]);
    }
#pragma unroll
    for (int o = 32; o; o >>= 1) {
        float m2 = __shfl_xor(m, o), s2 = __shfl_xor(s, o);
        float nm = fmaxf(m, m2);
        s = s * __expf(m - nm) + s2 * __expf(m2 - nm);
        m = nm;
    }
    __shared__ float sm[4], ss[4], sL;
    if ((tid & 63) == 0) { sm[tid >> 6] = m; ss[tid >> 6] = s; }
    __syncthreads();
    if (tid == 0) {
        m = sm[0]; s = ss[0];
        for (int wv = 1; wv < 4; ++wv) {
            float m2 = sm[wv], s2 = ss[wv];
            float nm = fmaxf(m, m2);
            s = s * __expf(m - nm) + s2 * __expf(m2 - nm);
            m = nm;
        }
        sL = m + __logf(s);
    }
    __syncthreads();
    const float L = sL;
    for (int i = tid; i < n4; i += 256) {
        f32x4 v = p4[i];
        v[0] -= L; v[1] -= L; v[2] -= L; v[3] -= L;
        p4[i] = v;
    }
    if (tid == 0) {
        for (int i = 0; i < head; ++i) p[i] -= L;
        for (int i = tail_start; i < VOC; ++i) p[i] -= L;
    }
}

extern "C" void kernel_launch(void* const* d_in, const int* in_sizes, int n_in,
                              void* d_out, int out_size, void* d_ws, size_t ws_size,
                              hipStream_t stream) {
    const int*   seq   = (const int*)d_in[0];
    const float* emb   = (const float*)d_in[1];
    const float* W_ih  = (const float*)d_in[2];
    const float* W_hh  = (const float*)d_in[3];
    const float* b_ih  = (const float*)d_in[4];
    const float* b_hh  = (const float*)d_in[5];
    const float* W_out = (const float*)d_in[6];
    const float* b_out = (const float*)d_in[7];
    float* out = (float*)d_out;

    size_t off = 0;
    auto carve = [&](size_t bytes) {
        void* p = (char*)d_ws + off;
        off += (bytes + 255) & ~(size_t)255;
        return p;
    };
    unsigned short* wWout = (unsigned short*)carve((size_t)VPAD * KDIM * 2);
    unsigned short* wWih  = (unsigned short*)carve((size_t)G4 * KDIM * 2);
    unsigned short* wX    = (unsigned short*)carve((size_t)SEQ * EMB * 2);
    unsigned short* wHs   = (unsigned short*)carve((size_t)SEQ * HID * 2);
    float*          wXg   = (float*)carve((size_t)SEQ * G4 * 4);
    float*          wBsum = (float*)carve((size_t)G4 * 4);
    unsigned long long* wHbuf = (unsigned long long*)carve((size_t)2 * HID * 8);

    // weight converts
    f32_to_bf16_k<<<(int)(((size_t)VPAD * KDIM / 4 + 255) / 256), 256, 0, stream>>>(
        W_out, wWout, (long)VOC * KDIM, (long)VPAD * KDIM);
    f32_to_bf16_k<<<(int)(((size_t)G4 * KDIM / 4 + 255) / 256), 256, 0, stream>>>(
        W_ih, wWih, (long)G4 * KDIM, (long)G4 * KDIM);
    embed_cvt_k<<<SEQ, 256, 0, stream>>>(seq, emb, wX);
    bias_sum_k<<<(G4 + 255) / 256, 256, 0, stream>>>(b_ih, b_hh, wBsum);

    // x_gates = x @ W_ih^T + (b_ih + b_hh)   [2048 x 4096]
    gemm_bt_k<<<dim3(SEQ / 128, G4 / 128), 256, 0, stream>>>(
        wX, wWih, wBsum, wXg, SEQ, G4, KDIM, G4);

    // sequential LSTM
    lstm_seq_k<<<256, 256, 0, stream>>>(W_hh, wXg, wHs, wHbuf);

    // logits = hs @ W_out^T + b_out  -> d_out  [2048 x 50257]
    gemm_bt_k<<<dim3(SEQ / 128, VPAD / 128), 256, 0, stream>>>(
        wHs, wWout, b_out, out, SEQ, VOC, KDIM, VOC);

    // in-place log_softmax
    log_softmax_k<<<SEQ, 256, 0, stream>>>(out);
}